// Round 1
// baseline (132.444 us; speedup 1.0000x reference)
//
#include <hip/hip_runtime.h>
#include <math.h>

// Problem constants (from reference)
#define BATCH 32
#define LSEQ 512
#define L2SEQ 514           // + 2 dumb atoms
#define NCH 5
#define GRID 32             // GRID_DIM_LOW
#define LATO 11
#define CA 5                // CUBES_AROUND
#define RES 0.5f            // RES_LOW
#define NPAIR (LATO * LATO) // 121

struct Params {
    float T;    // translation scalar (mincoords - CUBES_AROUND), same for all b/dims
    float D;    // dumb coordinate value
    int   lo;   // crop low index
};

// ---------------------------------------------------------------------------
// Phase 1: global max(|coords|) reduction -> derive dumb / translation / crop
// ---------------------------------------------------------------------------
__global__ void reduce_kernel(const float* __restrict__ coords, Params* __restrict__ p) {
    __shared__ float s[1024];
    float m = 0.0f;
    const int n = BATCH * LSEQ * 3;
    for (int i = threadIdx.x; i < n; i += 1024)
        m = fmaxf(m, fabsf(coords[i]));
    s[threadIdx.x] = m;
    __syncthreads();
    for (int w = 512; w > 0; w >>= 1) {
        if (threadIdx.x < w) s[threadIdx.x] = fmaxf(s[threadIdx.x], s[threadIdx.x + w]);
        __syncthreads();
    }
    if (threadIdx.x == 0) {
        float D  = s[0] + 10.0f;                       // dumb
        float mf = truncf(-D / RES);                   // mincoords scalar (same all b, dims)
        int box  = (int)ceilf(D / RES) - (int)mf + LATO;
        int voldim = box + 1;
        int lo = voldim / 2 - GRID / 2;
        p->T  = mf - (float)CA;                        // translation
        p->D  = D;
        p->lo = lo;
    }
}

// ---------------------------------------------------------------------------
// Zero the accumulation volume (ws is poisoned 0xAA before every timed call)
// ---------------------------------------------------------------------------
__global__ void zero_kernel(float* __restrict__ vol, int n) {
    int i = blockIdx.x * blockDim.x + threadIdx.x;
    if (i < n) vol[i] = 0.0f;
}

// ---------------------------------------------------------------------------
// Phase 2: scatter log-space contributions into the cropped volume.
// One thread per (atom, oy, oz); inner loop over ox (11 iters).
// ---------------------------------------------------------------------------
__global__ void scatter_kernel(const float* __restrict__ coords,
                               const int*   __restrict__ chan,
                               const float* __restrict__ radius,
                               const Params* __restrict__ p,
                               float* __restrict__ vol) {
    int gid  = blockIdx.x * blockDim.x + threadIdx.x;
    int atom = gid / NPAIR;
    int pair = gid - atom * NPAIR;
    if (atom >= BATCH * L2SEQ) return;
    int b = atom / L2SEQ;
    int l = atom - b * L2SEQ;

    const float T  = p->T;
    const int   lo = p->lo;
    const float D  = p->D;

    float cx, cy, cz, r;
    int ch;
    if (l < LSEQ) {
        int base = (b * LSEQ + l) * 3;
        cx = coords[base + 0];
        cy = coords[base + 1];
        cz = coords[base + 2];
        ch = chan[b * LSEQ + l];
        r  = radius[b * LSEQ + l];
    } else {
        float sgn = (l == LSEQ) ? -1.0f : 1.0f;        // first dumb is -D, second +D
        cx = cy = cz = sgn * D;
        ch = 0;
        r  = 0.5f;
    }
    r = r * 1.41421356f;   // RADIUS_SCALE = sqrt(2) in f32

    // coords_t = coords/res - translation  (>= ~4, so trunc == floor)
    float tx = cx / RES - T;
    float ty = cy / RES - T;
    float tz = cz / RES - T;
    float fx = truncf(tx), fy = truncf(ty), fz = truncf(tz);
    int dix = (int)fx, diy = (int)fy, diz = (int)fz;

    int oy = pair / LATO - CA;
    int oz = pair % LATO - CA;

    int gy = diy + oy + 1 - lo;
    int gz = diz + oz + 1 - lo;
    if ((unsigned)gy >= GRID || (unsigned)gz >= GRID) return;

    float rt    = r / RES;
    float denom = 0.8649f * (rt * rt);   // 0.93^2 * radius_t^2

    // centers = disc + off + 1 + 0.5*res ; delta = coords_t - centers
    float dy  = ty - (fy + (float)oy + 1.25f);
    float dz  = tz - (fz + (float)oz + 1.25f);
    float dyz = dy * dy + dz * dz;

    float* volb = vol + (size_t)(b * NCH + ch) * GRID * GRID * GRID;

    #pragma unroll
    for (int ox = -CA; ox <= CA; ++ox) {
        int gx = dix + ox + 1 - lo;
        if ((unsigned)gx >= GRID) continue;
        float dx    = tx - (fx + (float)ox + 1.25f);
        float dist2 = dx * dx + dyz;
        float dist  = sqrtf(dist2);            // mimic norm() then **2 rounding
        float e     = (dist * dist) / denom;
        if (e < 10.0f) {                        // exponent >= 10 entries contribute 0
            float val = log1pf(-expf(-e));
            atomicAdd(&volb[((size_t)gx * GRID + gy) * GRID + gz], val);
        }
    }
}

// ---------------------------------------------------------------------------
// Phase 3: out = 1 - exp(acc)
// ---------------------------------------------------------------------------
__global__ void finalize_kernel(const float* __restrict__ acc,
                                float* __restrict__ out, int n) {
    int i = blockIdx.x * blockDim.x + threadIdx.x;
    if (i < n) out[i] = 1.0f - expf(acc[i]);
}

extern "C" void kernel_launch(void* const* d_in, const int* in_sizes, int n_in,
                              void* d_out, int out_size, void* d_ws, size_t ws_size,
                              hipStream_t stream) {
    const float* coords = (const float*)d_in[0];
    const int*   chan   = (const int*)d_in[1];
    const float* radius = (const float*)d_in[2];
    float* out = (float*)d_out;

    Params* p  = (Params*)d_ws;
    float* vol = (float*)((char*)d_ws + 256);

    const int nvol = BATCH * NCH * GRID * GRID * GRID;   // 5,242,880

    zero_kernel<<<(nvol + 1023) / 1024, 1024, 0, stream>>>(vol, nvol);
    reduce_kernel<<<1, 1024, 0, stream>>>(coords, p);

    const int total = BATCH * L2SEQ * NPAIR;             // 1,990,208 threads
    scatter_kernel<<<(total + 255) / 256, 256, 0, stream>>>(coords, chan, radius, p, vol);

    finalize_kernel<<<(nvol + 1023) / 1024, 1024, 0, stream>>>(vol, out, nvol);
}

// Round 2
// 111.124 us; speedup vs baseline: 1.1919x; 1.1919x over previous
//
#include <hip/hip_runtime.h>
#include <math.h>

// Problem constants (from reference)
#define BATCH 32
#define LSEQ 512
#define L2SEQ 514           // + 2 dumb atoms
#define NATOMS (BATCH * L2SEQ)
#define NCH 5
#define GRID 32             // GRID_DIM_LOW
#define LATO 11
#define CA 5                // CUBES_AROUND
#define RES 0.5f            // RES_LOW
#define NVOL (BATCH * NCH * GRID * GRID * GRID)   // 5,242,880 floats
#define NCOORD (BATCH * LSEQ * 3)                 // 49,152 floats

// ---------------------------------------------------------------------------
// K1: zero the accumulation volume (float4) AND reduce max|coords| into
// slot via wave-shuffle + atomicMax on float bits (nonneg floats order as uints).
// slot must be zeroed beforehand (hipMemsetAsync).
// ---------------------------------------------------------------------------
__global__ void zero_reduce_kernel(const float* __restrict__ coords,
                                   unsigned* __restrict__ slot,
                                   float4* __restrict__ vol4) {
    int tid    = blockIdx.x * blockDim.x + threadIdx.x;
    int stride = gridDim.x * blockDim.x;

    for (int i = tid; i < NVOL / 4; i += stride)
        vol4[i] = make_float4(0.f, 0.f, 0.f, 0.f);

    float m = 0.0f;
    for (int i = tid; i < NCOORD; i += stride)
        m = fmaxf(m, fabsf(coords[i]));
    #pragma unroll
    for (int off = 32; off > 0; off >>= 1)
        m = fmaxf(m, __shfl_down(m, off));
    if ((threadIdx.x & 63) == 0 && m > 0.0f)
        atomicMax(slot, __float_as_uint(m));
}

// ---------------------------------------------------------------------------
// K2: scatter log-space contributions into the cropped volume.
// Block = 256 threads = 2 atoms; within each 128-lane half, pair = (oy,oz).
// ---------------------------------------------------------------------------
__global__ void __launch_bounds__(256) scatter_kernel(
        const float* __restrict__ coords,
        const int*   __restrict__ chan,
        const float* __restrict__ radius,
        const unsigned* __restrict__ slot,
        float* __restrict__ vol) {
    int atom = blockIdx.x * 2 + (threadIdx.x >> 7);
    int pair = threadIdx.x & 127;
    if (pair >= LATO * LATO || atom >= NATOMS) return;
    int b = atom / L2SEQ;
    int l = atom - b * L2SEQ;

    // Derive geometry params from the global max (uniform scalar path)
    float amax = __uint_as_float(*slot);
    float D  = amax + 10.0f;                       // dumb coordinate
    float mf = truncf(-D / RES);                   // mincoords scalar
    int box  = (int)ceilf(D / RES) - (int)mf + LATO;
    int lo   = (box + 1) / 2 - GRID / 2;           // crop low index
    float T  = mf - (float)CA;                     // translation

    float cx, cy, cz, r;
    int ch;
    if (l < LSEQ) {
        int base = (b * LSEQ + l) * 3;
        cx = coords[base + 0];
        cy = coords[base + 1];
        cz = coords[base + 2];
        ch = chan[b * LSEQ + l];
        r  = radius[b * LSEQ + l];
    } else {
        float sgn = (l == LSEQ) ? -1.0f : 1.0f;    // first dumb is -D, second +D
        cx = cy = cz = sgn * D;
        ch = 0;
        r  = 0.5f;
    }

    // radius_t = (r * sqrt(2)) / res  -- match reference op order
    float rs = r * 1.41421356f;
    float rt = rs / RES;
    float denom     = 0.8649f * (rt * rt);         // 0.93^2 * radius_t^2
    float lim       = 10.0f * denom;
    float inv_denom = 1.0f / denom;

    // coords_t = coords/res - translation (>= ~4, so trunc == floor)
    float tx = cx / RES - T;
    float ty = cy / RES - T;
    float tz = cz / RES - T;
    float fx = truncf(tx), fy = truncf(ty), fz = truncf(tz);
    int dix = (int)fx, diy = (int)fy, diz = (int)fz;

    int oy = pair / LATO - CA;
    int oz = pair % LATO - CA;

    int gy = diy + oy + 1 - lo;
    int gz = diz + oz + 1 - lo;
    if ((unsigned)gy >= GRID || (unsigned)gz >= GRID) return;

    // delta to voxel centers: centers = disc + off + 1 + 0.5*res
    float dy  = ty - (fy + (float)oy + 1.25f);
    float dz  = tz - (fz + (float)oz + 1.25f);
    float dyz = dy * dy + dz * dz;
    if (dyz >= lim) return;   // whole x-column masked (dx^2 >= 0.0625 > 0)

    float fracx = tx - fx - 1.25f;
    float* volb = vol + (b * NCH + ch) * (GRID * GRID * GRID);
    int yzoff = gy * GRID + gz;

    #pragma unroll
    for (int ox = -CA; ox <= CA; ++ox) {
        int gx = dix + ox + 1 - lo;
        if ((unsigned)gx >= GRID) continue;
        float dx    = fracx - (float)ox;
        float dist2 = dx * dx + dyz;
        float e     = dist2 * inv_denom;
        if (e < 10.0f) {                            // exponent >= 10 contributes 0
            float val = __logf(1.0f - __expf(-e));  // log1p(-exp(-e)), e >= 0.108
            atomicAdd(&volb[gx * (GRID * GRID) + yzoff], val);
        }
    }
}

// ---------------------------------------------------------------------------
// K3: out = 1 - exp(acc), vectorized
// ---------------------------------------------------------------------------
__global__ void finalize_kernel(const float4* __restrict__ acc,
                                float4* __restrict__ out) {
    int i = blockIdx.x * blockDim.x + threadIdx.x;
    if (i < NVOL / 4) {
        float4 a = acc[i];
        out[i] = make_float4(1.0f - __expf(a.x), 1.0f - __expf(a.y),
                             1.0f - __expf(a.z), 1.0f - __expf(a.w));
    }
}

extern "C" void kernel_launch(void* const* d_in, const int* in_sizes, int n_in,
                              void* d_out, int out_size, void* d_ws, size_t ws_size,
                              hipStream_t stream) {
    const float* coords = (const float*)d_in[0];
    const int*   chan   = (const int*)d_in[1];
    const float* radius = (const float*)d_in[2];
    float* out = (float*)d_out;

    unsigned* slot = (unsigned*)d_ws;
    float*    vol  = (float*)((char*)d_ws + 256);

    hipMemsetAsync(d_ws, 0, 64, stream);

    zero_reduce_kernel<<<1024, 256, 0, stream>>>(coords, slot, (float4*)vol);

    scatter_kernel<<<(NATOMS + 1) / 2, 256, 0, stream>>>(coords, chan, radius, slot, vol);

    finalize_kernel<<<(NVOL / 4 + 255) / 256, 256, 0, stream>>>((const float4*)vol,
                                                                (float4*)out);
}

// Round 3
// 98.012 us; speedup vs baseline: 1.3513x; 1.1338x over previous
//
#include <hip/hip_runtime.h>
#include <math.h>

// Problem constants (from reference)
#define BATCH 32
#define LSEQ  512
#define NCH   5
#define GRID  32
#define CA    5
#define LATO  11
#define NPAIR 121
#define XS    2                 // x-slices per block slab
#define SLABS (GRID / XS)       // 16 slabs per batch
#define TPB   512
#define VOXB  (XS * NCH * GRID * GRID)   // 10240 floats of LDS output slab

// One block = (batch b, x-slab). Everything (max-reduce, zero, bin, scatter,
// finalize) happens in this single kernel; output accumulates in LDS, so no
// global atomics, no zero/finalize passes over a 21 MB global volume.
__global__ void __launch_bounds__(TPB) fused_fieldmaker(
        const float* __restrict__ coords,
        const int*   __restrict__ chan,
        const float* __restrict__ radius,
        float*       __restrict__ out) {
    __shared__ float  vol[VOXB];     // 40 KB  (also reused as reduce scratch)
    __shared__ float4 alist[LSEQ];   // 8 KB   {ux, uy, uz, denom}
    __shared__ int    ameta[LSEQ];   // 2 KB   ch<<8 | (fxi+64)
    __shared__ int    s_cnt;
    __shared__ float  s_T, s_lo;

    const int tid = threadIdx.x;
    const int b   = blockIdx.x / SLABS;
    const int xs  = blockIdx.x - b * SLABS;
    const int x0  = xs * XS;

    // ---- Phase A: global max|coords| (exact, order-independent) ----
    float m = 0.0f;
    const float4* c4 = (const float4*)coords;
    for (int i = tid; i < BATCH * LSEQ * 3 / 4; i += TPB) {
        float4 v = c4[i];
        m = fmaxf(m, fmaxf(fmaxf(fabsf(v.x), fabsf(v.y)),
                           fmaxf(fabsf(v.z), fabsf(v.w))));
    }
    vol[tid] = m;
    __syncthreads();
    for (int w = TPB / 2; w >= 64; w >>= 1) {
        if (tid < w) vol[tid] = fmaxf(vol[tid], vol[tid + w]);
        __syncthreads();
    }
    if (tid < 64) {
        float mm = vol[tid];
        #pragma unroll
        for (int off = 32; off > 0; off >>= 1)
            mm = fmaxf(mm, __shfl_down(mm, off));
        if (tid == 0) {
            float D  = mm + 10.0f;                    // dumb coordinate
            float mf = truncf(-D * 2.0f);             // mincoords (= trunc(-D/res))
            int box  = (int)ceilf(D * 2.0f) - (int)mf + LATO;
            int lo   = (box + 1) / 2 - GRID / 2;      // crop low index
            s_T  = mf - (float)CA;                    // translation scalar
            s_lo = (float)lo;
            s_cnt = 0;
        }
    }
    __syncthreads();
    const float T   = s_T;
    const float flo = s_lo;

    // ---- Phase B: zero the LDS slab ----
    for (int i = tid; i < VOXB; i += TPB) vol[i] = 0.0f;
    // (barrier below also publishes s_cnt = 0)
    __syncthreads();

    // ---- Phase C: stage atoms of batch b whose 11^3 cube can touch this slab
    // (dumb atoms are >= 7 voxels outside the crop: provably zero, skipped) ----
    for (int l = tid; l < LSEQ; l += TPB) {
        int base = (b * LSEQ + l) * 3;
        float tx = coords[base + 0] * 2.0f - T;       // coords/res - translation
        float ty = coords[base + 1] * 2.0f - T;
        float tz = coords[base + 2] * 2.0f - T;
        float ux = tx - flo, uy = ty - flo, uz = tz - flo;  // crop frame
        int fxi = (int)floorf(ux);
        int fyi = (int)floorf(uy);
        int fzi = (int)floorf(uz);
        // x: ox = gx - fxi - 1 in [-5,5] for some gx in [x0, x0+XS-1]
        bool ok = (fxi >= x0 - 6) && (fxi <= x0 + XS + 4)
               && (fyi >= -6) && (fyi <= 35)          // y cube overlaps crop
               && (fzi >= -6) && (fzi <= 35);
        if (ok) {
            float r  = radius[b * LSEQ + l] * 1.41421356f;  // * RADIUS_SCALE
            float rt = r * 2.0f;                            // / res
            float denom = 0.8649f * (rt * rt);
            int slot = atomicAdd(&s_cnt, 1);
            alist[slot] = make_float4(ux, uy, uz, denom);
            ameta[slot] = (chan[b * LSEQ + l] << 8) | (fxi + 64);
        }
    }
    __syncthreads();

    // ---- Phase D: (atom x 121 pair) tasks, accumulate via LDS atomics ----
    const int cnt   = s_cnt;
    const int ntask = cnt * NPAIR;
    for (int t = tid; t < ntask; t += TPB) {
        int a = t / NPAIR;                // constant-divisor magic mul
        int p = t - a * NPAIR;
        int oy = p / LATO;                // 0..10
        int oz = p - oy * LATO;

        float4 A  = alist[a];
        int meta  = ameta[a];
        int fxi   = (meta & 255) - 64;
        int ch    = meta >> 8;
        float den = A.w;

        int fyi = (int)floorf(A.y);
        int fzi = (int)floorf(A.z);
        int gy  = fyi + oy - 4;           // fyi + (oy-5) + 1
        int gz  = fzi + oz - 4;
        if ((unsigned)gy >= GRID || (unsigned)gz >= GRID) continue;

        float dy  = (A.y - 0.25f) - (float)gy;   // atom - voxel center
        float dz  = (A.z - 0.25f) - (float)gz;
        float dyz = dy * dy + dz * dz;
        if (dyz >= 10.0f * den) continue;        // whole x-pair masked

        float rx    = A.x - 0.25f;
        int   lbase = (gy << 5) + gz;
        #pragma unroll
        for (int s = 0; s < XS; ++s) {
            int gx = x0 + s;
            int od = gx - fxi;                   // ox+1, valid in [-4,6]
            if (od < -4 || od > 6) continue;
            float dx = rx - (float)gx;
            float e  = (dx * dx + dyz) / den;
            if (e < 10.0f) {                     // exponent >= 10 contributes 0
                float val = __logf(1.0f - __expf(-e));  // log1p(-exp(-e))
                atomicAdd(&vol[(s * NCH + ch) * 1024 + lbase], val);
            }
        }
    }
    __syncthreads();

    // ---- Phase E: finalize + coalesced store ----
    for (int i = tid; i < VOXB; i += TPB) {
        int s   = i / (NCH * 1024);
        int rem = i - s * (NCH * 1024);
        int c   = rem >> 10;
        int yz  = rem & 1023;
        out[(((size_t)b * NCH + c) * GRID + (x0 + s)) * 1024 + yz] =
            1.0f - __expf(vol[i]);
    }
}

extern "C" void kernel_launch(void* const* d_in, const int* in_sizes, int n_in,
                              void* d_out, int out_size, void* d_ws, size_t ws_size,
                              hipStream_t stream) {
    const float* coords = (const float*)d_in[0];
    const int*   chan   = (const int*)d_in[1];
    const float* radius = (const float*)d_in[2];
    float* out = (float*)d_out;

    fused_fieldmaker<<<BATCH * SLABS, TPB, 0, stream>>>(coords, chan, radius, out);
}

// Round 4
// 86.803 us; speedup vs baseline: 1.5258x; 1.1291x over previous
//
#include <hip/hip_runtime.h>
#include <math.h>

// Problem constants (from reference)
#define BATCH 32
#define LSEQ  512
#define NCH   5
#define GRID  32
#define TPB   512
#define NPAIR 81                 // 9x9 live window (|offset|<=4): |d|>=4.25 -> e>=10.44>10, exact
#define ROWS  33                 // slab row stride (bank-conflict diagonal swizzle)
#define CHSZ  (ROWS * 32)        // 1056 floats per channel slab
#define VOXB  (NCH * CHSZ)       // 5280 floats (20.6 KB)

// ---------------------------------------------------------------------------
// K0: global max|coords| via wave-reduce + atomicMax on float bits.
// slot must be zeroed first (nonneg floats order as uints).
// ---------------------------------------------------------------------------
__global__ void __launch_bounds__(256) max_kernel(const float4* __restrict__ c4,
                                                  unsigned* __restrict__ slot) {
    int i = blockIdx.x * 256 + threadIdx.x;      // 48*256 = 12288 = NCOORD/4 exactly
    float4 v = c4[i];
    float m = fmaxf(fmaxf(fabsf(v.x), fabsf(v.y)), fmaxf(fabsf(v.z), fabsf(v.w)));
    #pragma unroll
    for (int off = 32; off > 0; off >>= 1)
        m = fmaxf(m, __shfl_down(m, off));
    if ((threadIdx.x & 63) == 0)
        atomicMax(slot, __float_as_uint(m));
}

// ---------------------------------------------------------------------------
// Main: one block = (batch b, x-slice gx). Output slab lives in LDS.
// ---------------------------------------------------------------------------
__global__ void __launch_bounds__(TPB) fused_fieldmaker(
        const float* __restrict__ coords,
        const int*   __restrict__ chan,
        const float* __restrict__ radius,
        const unsigned* __restrict__ slot,
        float*       __restrict__ out) {
    __shared__ float  vol[VOXB];     // 20.6 KB slab, rows stride 33
    __shared__ float4 alist[LSEQ];   // {ex, ay, az, inv_den}
    __shared__ int    ameta[LSEQ];   // (fy-4+16) | (fz-4+16)<<8 | ch<<16
    __shared__ int    s_cnt;

    const int tid = threadIdx.x;
    const int b   = blockIdx.x >> 5;
    const int gx  = blockIdx.x & 31;          // this block's crop x-slice

    // ---- derive geometry params from the global max (uniform, ~12 ops) ----
    float amax = __uint_as_float(*slot);
    float D  = amax + 10.0f;                  // dumb coordinate
    float mf = truncf(-D * 2.0f);             // mincoords (= trunc(-D/res))
    int box  = (int)ceilf(D * 2.0f) - (int)mf + 11;
    int lo   = (box + 1) / 2 - GRID / 2;      // crop low index
    float Tl = (mf - 5.0f) + (float)lo;       // translation + crop shift

    // ---- zero slab ----
    float4* vol4 = (float4*)vol;
    for (int i = tid; i < VOXB / 4; i += TPB)
        vol4[i] = make_float4(0.f, 0.f, 0.f, 0.f);
    if (tid == 0) s_cnt = 0;
    __syncthreads();

    // ---- stage atoms whose x-distance to this slice passes the EXACT e<10
    //      x-cut (subsumes the reference's integer offset window; dumb atoms
    //      are ~20 voxels outside the crop -> provably zero, skipped) ----
    {
        int base = (b * LSEQ + tid) * 3;
        float ux = coords[base + 0] * 2.0f - Tl;   // crop-frame continuous coords
        float uy = coords[base + 1] * 2.0f - Tl;
        float uz = coords[base + 2] * 2.0f - Tl;
        int fyi = (int)floorf(uy);
        int fzi = (int)floorf(uz);

        float r   = radius[b * LSEQ + tid] * 1.41421356f;  // * RADIUS_SCALE
        float rt  = r * 2.0f;                              // / res
        float den = 0.8649f * (rt * rt);                   // 0.93^2 * rt^2
        float inv = 1.0f / den;

        float dx = ux - 0.25f - (float)gx;                 // atom - voxel center x
        float ex = dx * dx * inv;

        if (ex < 10.0f && fyi >= -5 && fyi <= 36 && fzi >= -5 && fzi <= 36) {
            int slotl = atomicAdd(&s_cnt, 1);
            alist[slotl] = make_float4(ex, uy - 0.25f, uz - 0.25f, inv);
            ameta[slotl] = (fyi + 12) | ((fzi + 12) << 8)
                         | (chan[b * LSEQ + tid] << 16);   // (f-4)+16 bias
        }
    }
    __syncthreads();

    // ---- scatter: (atom x 81 pair) tasks, LDS float atomics ----
    const int ntask = s_cnt * NPAIR;
    for (int t = tid; t < ntask; t += TPB) {
        unsigned a = (unsigned)t / NPAIR;
        unsigned p = (unsigned)t - a * NPAIR;
        unsigned oy = p / 9u;
        unsigned oz = p - oy * 9u;

        float4 A = alist[a];
        int meta = ameta[a];
        int gy = (meta & 255) - 16 + (int)oy;   // fyi - 4 + oy
        int gz = ((meta >> 8) & 255) - 16 + (int)oz;
        if ((unsigned)gy >= 32u || (unsigned)gz >= 32u) continue;

        float dy  = A.y - (float)gy;
        float dz  = A.z - (float)gz;
        float e   = A.x + (dy * dy + dz * dz) * A.w;
        if (e < 10.0f) {                         // exponent >= 10 contributes 0
            float val = __logf(1.0f - __expf(-e));     // log1p(-exp(-e))
            atomicAdd(&vol[(meta >> 16) * CHSZ + gy * ROWS + gz], val);
        }
    }
    __syncthreads();

    // ---- finalize + coalesced store: out[b][c][gx][gy][gz] = 1-exp(acc) ----
    for (int i = tid; i < NCH * 256; i += TPB) {      // float4 granularity
        int c   = i >> 8;
        int r4  = i & 255;
        int gy  = r4 >> 3;
        int gz0 = (r4 & 7) << 2;
        const float* v = &vol[c * CHSZ + gy * ROWS + gz0];
        float4 o = make_float4(1.0f - __expf(v[0]), 1.0f - __expf(v[1]),
                               1.0f - __expf(v[2]), 1.0f - __expf(v[3]));
        ((float4*)out)[(((size_t)b * NCH + c) * GRID + gx) * 256 + r4] = o;
    }
}

extern "C" void kernel_launch(void* const* d_in, const int* in_sizes, int n_in,
                              void* d_out, int out_size, void* d_ws, size_t ws_size,
                              hipStream_t stream) {
    const float* coords = (const float*)d_in[0];
    const int*   chan   = (const int*)d_in[1];
    const float* radius = (const float*)d_in[2];
    float* out = (float*)d_out;
    unsigned* slot = (unsigned*)d_ws;

    hipMemsetAsync(slot, 0, 4, stream);
    max_kernel<<<48, 256, 0, stream>>>((const float4*)coords, slot);
    fused_fieldmaker<<<BATCH * GRID, TPB, 0, stream>>>(coords, chan, radius, slot, out);
}

// Round 5
// 85.563 us; speedup vs baseline: 1.5479x; 1.0145x over previous
//
#include <hip/hip_runtime.h>
#include <math.h>

// Problem constants (from reference)
#define BATCH 32
#define LSEQ  512
#define NCH   5
#define GRID  32
#define TPB   512
#define ROWS  33                 // slab row stride (bank-conflict diagonal swizzle)
#define CHSZ  (ROWS * 32)        // 1056 floats per channel slab
#define VOXB  (NCH * CHSZ)       // 5280 floats (20.6 KB)

__device__ __forceinline__ float rfl(float x) {
    return __uint_as_float(__builtin_amdgcn_readfirstlane(__float_as_uint(x)));
}

// ---------------------------------------------------------------------------
// K0: global max|coords| via wave-reduce + atomicMax on float bits.
// slot must be zeroed first (nonneg floats order as uints).
// ---------------------------------------------------------------------------
__global__ void __launch_bounds__(256) max_kernel(const float4* __restrict__ c4,
                                                  unsigned* __restrict__ slot) {
    int i = blockIdx.x * 256 + threadIdx.x;      // 48*256 = 12288 = NCOORD/4 exactly
    float4 v = c4[i];
    float m = fmaxf(fmaxf(fabsf(v.x), fabsf(v.y)), fmaxf(fabsf(v.z), fabsf(v.w)));
    #pragma unroll
    for (int off = 32; off > 0; off >>= 1)
        m = fmaxf(m, __shfl_down(m, off));
    if ((threadIdx.x & 63) == 0)
        atomicMax(slot, __float_as_uint(m));
}

// ---------------------------------------------------------------------------
// Main: one block = (batch b, x-slice gx). Output slab lives in LDS.
// Scatter phase: one WAVE per atom, atom state scalarized (SGPR), pair
// (oy,oz) mapped to lanes in two fixed passes (64 + 17) with hoisted
// per-lane offsets -> no per-task div/mod, no per-lane atom reloads.
// ---------------------------------------------------------------------------
__global__ void __launch_bounds__(TPB) fused_fieldmaker(
        const float* __restrict__ coords,
        const int*   __restrict__ chan,
        const float* __restrict__ radius,
        const unsigned* __restrict__ slot,
        float*       __restrict__ out) {
    __shared__ float  vol[VOXB];     // 20.6 KB slab, rows stride 33
    __shared__ float4 alist[LSEQ];   // {ex, ay, az, inv_den}
    __shared__ int    ameta[LSEQ];   // (fy-4+16) | (fz-4+16)<<8 | ch<<16
    __shared__ int    s_cnt;

    const int tid = threadIdx.x;
    const int b   = blockIdx.x >> 5;
    const int gx  = blockIdx.x & 31;          // this block's crop x-slice

    // ---- derive geometry params from the global max (uniform, ~12 ops) ----
    float amax = __uint_as_float(*slot);
    float D  = amax + 10.0f;                  // dumb coordinate
    float mf = truncf(-D * 2.0f);             // mincoords (= trunc(-D/res))
    int box  = (int)ceilf(D * 2.0f) - (int)mf + 11;
    int lo   = (box + 1) / 2 - GRID / 2;      // crop low index
    float Tl = (mf - 5.0f) + (float)lo;       // translation + crop shift

    // ---- zero slab ----
    float4* vol4 = (float4*)vol;
    for (int i = tid; i < VOXB / 4; i += TPB)
        vol4[i] = make_float4(0.f, 0.f, 0.f, 0.f);
    if (tid == 0) s_cnt = 0;
    __syncthreads();

    // ---- stage atoms passing the EXACT e<10 x-cut for this slice
    // (subsumes the reference's integer offset window; dumb atoms are
    //  ~20 voxels outside the crop -> provably zero, skipped) ----
    {
        int base = (b * LSEQ + tid) * 3;
        float ux = coords[base + 0] * 2.0f - Tl;   // crop-frame continuous coords
        float uy = coords[base + 1] * 2.0f - Tl;
        float uz = coords[base + 2] * 2.0f - Tl;
        int fyi = (int)floorf(uy);
        int fzi = (int)floorf(uz);

        float r   = radius[b * LSEQ + tid] * 1.41421356f;  // * RADIUS_SCALE
        float rt  = r * 2.0f;                              // / res
        float den = 0.8649f * (rt * rt);                   // 0.93^2 * rt^2
        float inv = 1.0f / den;

        float dx = ux - 0.25f - (float)gx;                 // atom - voxel center x
        float ex = dx * dx * inv;

        if (ex < 10.0f && fyi >= -5 && fyi <= 36 && fzi >= -5 && fzi <= 36) {
            int slotl = atomicAdd(&s_cnt, 1);
            alist[slotl] = make_float4(ex, uy - 0.25f, uz - 0.25f, inv);
            ameta[slotl] = (fyi + 12) | ((fzi + 12) << 8)
                         | (chan[b * LSEQ + tid] << 16);   // (f-4)+16 bias
        }
    }
    __syncthreads();

    // ---- scatter: one wave per atom, 81-pair window in two lane passes ----
    const int cnt  = s_cnt;
    const int lane = tid & 63;
    const int wid  = tid >> 6;
    // hoisted per-lane pair constants
    const int oyA = lane / 9, ozA = lane - 9 * oyA;          // pairs 0..63
    const int pB  = lane + 64;                               // pairs 64..80
    const int oyB = pB / 9,  ozB = pB - 9 * oyB;             // (valid lane<17)
    const float oyAf = (float)oyA, ozAf = (float)ozA;
    const float oyBf = (float)oyB, ozBf = (float)ozB;
    const int adA = oyA * ROWS + ozA;
    const int adB = oyB * ROWS + ozB;

    for (int a = wid; a < cnt; a += TPB / 64) {
        float4 A = alist[a];                  // wave-uniform -> broadcast read
        int m    = __builtin_amdgcn_readfirstlane(ameta[a]);
        float ex  = rfl(A.x);
        float ay  = rfl(A.y);
        float az  = rfl(A.z);
        float inv = rfl(A.w);
        int fy4 = (m & 255) - 16;             // fyi - 4
        int fz4 = ((m >> 8) & 255) - 16;
        int ch  = m >> 16;
        float ayb = ay - (float)fy4;          // dy = ayb - oyf
        float azb = az - (float)fz4;
        int base  = ch * CHSZ + fy4 * ROWS + fz4;   // + hoisted lane offset

        // pass A: pairs 0..63
        {
            float dy = ayb - oyAf, dz = azb - ozAf;
            float e  = fmaf(fmaf(dy, dy, dz * dz), inv, ex);
            if ((unsigned)(fy4 + oyA) < 32u && (unsigned)(fz4 + ozA) < 32u
                && e < 10.0f) {
                float val = __logf(1.0f - __expf(-e));   // log1p(-exp(-e))
                atomicAdd(&vol[base + adA], val);
            }
        }
        // pass B: pairs 64..80 (lanes 0..16)
        {
            float dy = ayb - oyBf, dz = azb - ozBf;
            float e  = fmaf(fmaf(dy, dy, dz * dz), inv, ex);
            if (lane < 17 && (unsigned)(fy4 + oyB) < 32u
                && (unsigned)(fz4 + ozB) < 32u && e < 10.0f) {
                float val = __logf(1.0f - __expf(-e));
                atomicAdd(&vol[base + adB], val);
            }
        }
    }
    __syncthreads();

    // ---- finalize + coalesced store: out[b][c][gx][gy][gz] = 1-exp(acc) ----
    for (int i = tid; i < NCH * 256; i += TPB) {      // float4 granularity
        int c   = i >> 8;
        int r4  = i & 255;
        int gy  = r4 >> 3;
        int gz0 = (r4 & 7) << 2;
        const float* v = &vol[c * CHSZ + gy * ROWS + gz0];
        float4 o = make_float4(1.0f - __expf(v[0]), 1.0f - __expf(v[1]),
                               1.0f - __expf(v[2]), 1.0f - __expf(v[3]));
        ((float4*)out)[(((size_t)b * NCH + c) * GRID + gx) * 256 + r4] = o;
    }
}

extern "C" void kernel_launch(void* const* d_in, const int* in_sizes, int n_in,
                              void* d_out, int out_size, void* d_ws, size_t ws_size,
                              hipStream_t stream) {
    const float* coords = (const float*)d_in[0];
    const int*   chan   = (const int*)d_in[1];
    const float* radius = (const float*)d_in[2];
    float* out = (float*)d_out;
    unsigned* slot = (unsigned*)d_ws;

    hipMemsetAsync(slot, 0, 4, stream);
    max_kernel<<<48, 256, 0, stream>>>((const float4*)coords, slot);
    fused_fieldmaker<<<BATCH * GRID, TPB, 0, stream>>>(coords, chan, radius, slot, out);
}